// Round 3
// baseline (387.174 us; speedup 1.0000x reference)
//
#include <hip/hip_runtime.h>

// Fused 2-layer GRU via MFMA, persistent-weight, 2-wave gate-split.
// S=256, B=8192, IN=1, H=32, L=2.
//
// Each block (128 thr = 2 waves) owns 16 batch elements for all 256 steps.
// Wave w computes gate rows [16w,16w+16) of r,z,n for both layers:
//   gates[16 x 16batch] = W(A-frag, persistent regs) @ h(B-frag)
// via v_mfma_f32_16x16x32_bf16 (K=32 == H). h carried hi/lo split-bf16.
// Biases pre-folded into MFMA C operands; sigmoid/tanh exp2 scale baked
// into weights at init. The two waves exchange their h-halves through LDS
// with 2 __syncthreads per step. L1's hh-side MFMA chains depend only on
// the previous step's h1, so they issue at the top of the step to overlap
// L0's epilogue latency.

#define S_LEN 256
#define B_SZ  8192
#define H_SZ  32
#define PAD   36     // LDS row stride (floats)

typedef __attribute__((ext_vector_type(8))) short short8;  // 8 bf16
typedef __attribute__((ext_vector_type(4))) float f32x4;   // MFMA C/D

#define MFMA(a, b, c) __builtin_amdgcn_mfma_f32_16x16x32_bf16(a, b, c, 0, 0, 0)

#if __has_builtin(__builtin_amdgcn_exp2f)
#define EXP2F(x) __builtin_amdgcn_exp2f(x)
#else
#define EXP2F(x) exp2f(x)
#endif
#if __has_builtin(__builtin_amdgcn_rcpf)
#define RCPF(x) __builtin_amdgcn_rcpf(x)
#else
#define RCPF(x) (1.0f / (x))
#endif

// Pre-scaled activations: exp2 constant baked into the operand upstream.
__device__ __forceinline__ float sigm_pre(float p) {   // p = -log2e * v
    return RCPF(1.0f + EXP2F(p));
}
__device__ __forceinline__ float tanh_pre(float p) {   // p = 2*log2e * v
    return 1.0f - 2.0f * RCPF(1.0f + EXP2F(p));
}

__device__ __forceinline__ short bf_rne(float f) {
    union { float f; unsigned u; } x; x.f = f;
    unsigned u = x.u + 0x7fffu + ((x.u >> 16) & 1u);
    return (short)(u >> 16);
}

// fp32 -> hi (truncated bf16) + lo (residual bf16); combined rel err ~2^-17.
__device__ __forceinline__ void split8(const float v[8], short8& hi, short8& lo) {
#pragma unroll
    for (int e = 0; e < 8; ++e) {
        union { float f; unsigned u; } x; x.f = v[e];
        unsigned uh = x.u & 0xffff0000u;
        hi[e] = (short)(uh >> 16);
        union { unsigned u; float f; } hf; hf.u = uh;
        union { float f; unsigned u; } l; l.f = v[e] - hf.f;
        lo[e] = (short)(l.u >> 16);
    }
}

__global__ __launch_bounds__(128) void gru_mfma2(
    const float* __restrict__ x,      // (S,B,1)
    const float* __restrict__ h_in,   // (2,B,H)
    const float* __restrict__ W_ih0,  // (96,1)
    const float* __restrict__ W_hh0,  // (96,32)
    const float* __restrict__ b_ih0,  // (96)
    const float* __restrict__ b_hh0,  // (96)
    const float* __restrict__ W_ih1,  // (96,32)
    const float* __restrict__ W_hh1,  // (96,32)
    const float* __restrict__ b_ih1,  // (96)
    const float* __restrict__ b_hh1,  // (96)
    const float* __restrict__ W_out,  // (1,32)
    const float* __restrict__ b_out,  // (1)
    float* __restrict__ out)          // y (S*B) then h_state (2,B,H)
{
    __shared__ __align__(16) float sh0[16 * PAD];
    __shared__ __align__(16) float sh1[16 * PAD];
    __shared__ float yp[32];

    const int tid  = threadIdx.x;
    const int w    = tid >> 6;        // wave 0/1: gate rows [16w,16w+16)
    const int lane = tid & 63;
    const int n    = lane & 15;       // batch col (B/D) & gate-row (A) index
    const int q    = lane >> 4;       // quad
    const int bn   = blockIdx.x * 16 + n;

    const float SRZ = -1.4426950408889634f;  // -log2(e)   (sigmoid gates)
    const float SN  =  2.8853900817779268f;  //  2*log2(e) (tanh gate)

    // ---- persistent weight A-frags: A[m=n][k=q*8+e], pre-scaled bf16 ----
    short8 A0[3], Ai1[3], Ah1[3];            // t: 0=r, 1=z, 2=n
#pragma unroll
    for (int t = 0; t < 3; ++t) {
        const float sc = (t < 2) ? SRZ : SN;
        const int row = 32 * t + 16 * w + n;
        const float* p0 = W_hh0 + row * H_SZ + q * 8;
        const float* p1 = W_ih1 + row * H_SZ + q * 8;
        const float* p2 = W_hh1 + row * H_SZ + q * 8;
#pragma unroll
        for (int e = 0; e < 8; ++e) {
            A0[t][e]  = bf_rne(p0[e] * sc);
            Ai1[t][e] = bf_rne(p1[e] * sc);
            Ah1[t][e] = bf_rne(p2[e] * sc);
        }
    }

    // ---- bias C-inits (fp32, scaled). D row = q*4+r, col = n. ----
    f32x4 Cb0[3], C1rz[2], C1ni, C1nh;
#pragma unroll
    for (int t = 0; t < 3; ++t)
#pragma unroll
        for (int r = 0; r < 4; ++r) {
            const int g = 32 * t + 16 * w + 4 * q + r;
            if (t < 2) {
                const float sc = SRZ;
                Cb0[t][r]  = sc * (b_ih0[g] + b_hh0[g]);
                C1rz[t][r] = sc * (b_ih1[g] + b_hh1[g]);
            } else {
                Cb0[2][r] = SN * b_hh0[g];   // n-gate: b_hh stays on gh side
                C1ni[r]   = SN * b_ih1[g];
                C1nh[r]   = SN * b_hh1[g];
            }
        }

    // ---- layer-0 input weights + head weights (per-lane j = 16w+4q+r) ----
    float wi0r[4], wi0z[4], wi0n[4], bi0n[4], wo[4];
#pragma unroll
    for (int r = 0; r < 4; ++r) {
        const int j = 16 * w + 4 * q + r;
        wi0r[r] = SRZ * W_ih0[j];
        wi0z[r] = SRZ * W_ih0[32 + j];
        wi0n[r] = SN  * W_ih0[64 + j];
        bi0n[r] = SN  * b_ih0[64 + j];
        wo[r]   = W_out[j];
    }
    const float bout = b_out[0];

    // ---- h state: D-layout fp32 (this wave's 16-row half) + full B-frags ----
    float h0d[4], h1d[4];
#pragma unroll
    for (int r = 0; r < 4; ++r) {
        const int j = 16 * w + 4 * q + r;
        h0d[r] = h_in[bn * H_SZ + j];
        h1d[r] = h_in[B_SZ * H_SZ + bn * H_SZ + j];
    }
    short8 B0hi, B0lo, B1hi, B1lo;
    {
        float v[8];
        const float* p = h_in + bn * H_SZ + q * 8;
#pragma unroll
        for (int e = 0; e < 8; ++e) v[e] = p[e];
        split8(v, B0hi, B0lo);
        p += B_SZ * H_SZ;
#pragma unroll
        for (int e = 0; e < 8; ++e) v[e] = p[e];
        split8(v, B1hi, B1lo);
    }

    float xcur = x[bn];

#pragma unroll 1
    for (int t = 0; t < S_LEN; ++t) {
        const float xnext = (t + 1 < S_LEN) ? x[(t + 1) * B_SZ + bn] : 0.0f;

        // -- early issue: L1 hh-side chains (depend only on prev-step h1) --
        f32x4 grz0, grz1, ghn;
        grz0 = MFMA(Ah1[0], B1hi, C1rz[0]); grz0 = MFMA(Ah1[0], B1lo, grz0);
        grz1 = MFMA(Ah1[1], B1hi, C1rz[1]); grz1 = MFMA(Ah1[1], B1lo, grz1);
        ghn  = MFMA(Ah1[2], B1hi, C1nh);    ghn  = MFMA(Ah1[2], B1lo, ghn);

        // -- layer 0: gh0 = Whh0_half @ h0 (+ folded biases) --
        f32x4 g0r, g0z, g0n;
        g0r = MFMA(A0[0], B0hi, Cb0[0]); g0r = MFMA(A0[0], B0lo, g0r);
        g0z = MFMA(A0[1], B0hi, Cb0[1]); g0z = MFMA(A0[1], B0lo, g0z);
        g0n = MFMA(A0[2], B0hi, Cb0[2]); g0n = MFMA(A0[2], B0lo, g0n);

        float hv4[4];
#pragma unroll
        for (int r = 0; r < 4; ++r) {
            const float rg = sigm_pre(fmaf(xcur, wi0r[r], g0r[r]));
            const float zg = sigm_pre(fmaf(xcur, wi0z[r], g0z[r]));
            const float ng = tanh_pre(fmaf(rg, g0n[r],
                                           fmaf(xcur, wi0n[r], bi0n[r])));
            const float hv = fmaf(zg, h0d[r] - ng, ng);
            h0d[r] = hv;
            hv4[r] = hv;
        }
        // exchange h0 halves: lane (n,q,w) holds h0[16w+4q+r][n], r=0..3
        *(float4*)&sh0[n * PAD + 16 * w + 4 * q] =
            make_float4(hv4[0], hv4[1], hv4[2], hv4[3]);
        __syncthreads();
        {
            const float4 ra = *(const float4*)&sh0[n * PAD + q * 8];
            const float4 rb = *(const float4*)&sh0[n * PAD + q * 8 + 4];
            const float v[8] = {ra.x, ra.y, ra.z, ra.w, rb.x, rb.y, rb.z, rb.w};
            split8(v, B0hi, B0lo);
        }

        // -- layer 1: ih-side chains on fresh h0 --
        grz0 = MFMA(Ai1[0], B0hi, grz0); grz0 = MFMA(Ai1[0], B0lo, grz0);
        grz1 = MFMA(Ai1[1], B0hi, grz1); grz1 = MFMA(Ai1[1], B0lo, grz1);
        f32x4 gin;
        gin  = MFMA(Ai1[2], B0hi, C1ni); gin  = MFMA(Ai1[2], B0lo, gin);

        float ysum = 0.0f;
#pragma unroll
        for (int r = 0; r < 4; ++r) {
            const float rg = sigm_pre(grz0[r]);
            const float zg = sigm_pre(grz1[r]);
            const float ng = tanh_pre(fmaf(rg, ghn[r], gin[r]));
            const float hv = fmaf(zg, h1d[r] - ng, ng);
            h1d[r] = hv;
            hv4[r] = hv;
            ysum = fmaf(hv, wo[r], ysum);
        }
        // reduce ysum over q (hidden dim within this wave's half)
        ysum += __shfl_xor(ysum, 16);
        ysum += __shfl_xor(ysum, 32);

        *(float4*)&sh1[n * PAD + 16 * w + 4 * q] =
            make_float4(hv4[0], hv4[1], hv4[2], hv4[3]);
        if (lane < 16) yp[w * 16 + n] = ysum;
        __syncthreads();
        {
            const float4 ra = *(const float4*)&sh1[n * PAD + q * 8];
            const float4 rb = *(const float4*)&sh1[n * PAD + q * 8 + 4];
            const float v[8] = {ra.x, ra.y, ra.z, ra.w, rb.x, rb.y, rb.z, rb.w};
            split8(v, B1hi, B1lo);
        }
        if (w == 0 && lane < 16)
            out[t * B_SZ + bn] = yp[n] + yp[16 + n] + bout;

        xcur = xnext;
    }

    // final h_state: out = y (S*B) ++ h0 (B*H) ++ h1 (B*H)
    const int jbase = 16 * w + 4 * q;
    *(float4*)&out[S_LEN * B_SZ + bn * H_SZ + jbase] =
        make_float4(h0d[0], h0d[1], h0d[2], h0d[3]);
    *(float4*)&out[S_LEN * B_SZ + B_SZ * H_SZ + bn * H_SZ + jbase] =
        make_float4(h1d[0], h1d[1], h1d[2], h1d[3]);
}

extern "C" void kernel_launch(void* const* d_in, const int* in_sizes, int n_in,
                              void* d_out, int out_size, void* d_ws, size_t ws_size,
                              hipStream_t stream) {
    (void)in_sizes; (void)n_in; (void)out_size; (void)d_ws; (void)ws_size;
    const float* x     = (const float*)d_in[0];
    const float* h_in  = (const float*)d_in[1];
    const float* W_ih0 = (const float*)d_in[2];
    const float* W_hh0 = (const float*)d_in[3];
    const float* b_ih0 = (const float*)d_in[4];
    const float* b_hh0 = (const float*)d_in[5];
    const float* W_ih1 = (const float*)d_in[6];
    const float* W_hh1 = (const float*)d_in[7];
    const float* b_ih1 = (const float*)d_in[8];
    const float* b_hh1 = (const float*)d_in[9];
    const float* W_out = (const float*)d_in[10];
    const float* b_out = (const float*)d_in[11];

    dim3 grid(B_SZ / 16);   // 512 blocks x 2 waves = 1024 waves (1 per SIMD)
    dim3 block(128);
    gru_mfma2<<<grid, block, 0, stream>>>(x, h_in, W_ih0, W_hh0, b_ih0, b_hh0,
                                          W_ih1, W_hh1, b_ih1, b_hh1,
                                          W_out, b_out, (float*)d_out);
}

// Round 4
// 360.976 us; speedup vs baseline: 1.0726x; 1.0726x over previous
//
#include <hip/hip_runtime.h>

// Fused 2-layer GRU via MFMA, round 4: latency-lean recurrence.
// S=256, B=8192, IN=1, H=32, L=2.
//
// Geometry (unchanged from R3): 512 blocks x 2 waves; each block owns 16
// batch elements, wave w owns gate rows [16w,16w+16) of r,z,n for both
// layers. Changes vs R3, all aimed at the per-step critical path:
//  - h carried as SINGLE RNE bf16 (no hi/lo split): 9 MFMAs/step (was 18),
//    all dependency chains depth <= 1, no residual math.
//  - ONE __syncthreads per step (was 2): h1 written at end of step t is
//    only read after step t+1's barrier. sh0/sh1 double-buffered to keep
//    cross-step write-after-read safe.
//  - L1 hh-side and ih-side MFMAs in independent accumulators (+4 adds/tile)
//    instead of chained.
//  - y[t] computed from the fp32 h1 values read back for step t+1's B1
//    fragment (they are exactly h1 after step t) -> no yp LDS exchange.
//    y[S-1] handled after the loop with one extra barrier+read.

#define S_LEN 256
#define B_SZ  8192
#define H_SZ  32
#define PAD   36     // LDS row stride (floats): b128 rows, 2-way banks (free)

typedef __attribute__((ext_vector_type(8))) short short8;  // 8 bf16
typedef __attribute__((ext_vector_type(4))) float f32x4;   // MFMA C/D

#define MFMA(a, b, c) __builtin_amdgcn_mfma_f32_16x16x32_bf16(a, b, c, 0, 0, 0)

#if __has_builtin(__builtin_amdgcn_exp2f)
#define EXP2F(x) __builtin_amdgcn_exp2f(x)
#else
#define EXP2F(x) exp2f(x)
#endif
#if __has_builtin(__builtin_amdgcn_rcpf)
#define RCPF(x) __builtin_amdgcn_rcpf(x)
#else
#define RCPF(x) (1.0f / (x))
#endif

// Pre-scaled activations (exp2 constant folded into weights/biases):
__device__ __forceinline__ float sigm_pre(float p) {   // p = -log2e * v
    return RCPF(1.0f + EXP2F(p));
}
__device__ __forceinline__ float tanh_pre(float p) {   // p = 2*log2e * v
    return 1.0f - 2.0f * RCPF(1.0f + EXP2F(p));
}

__device__ __forceinline__ short bf_rne(float f) {
    union { float f; unsigned u; } x; x.f = f;
    unsigned u = x.u + 0x7fffu + ((x.u >> 16) & 1u);
    return (short)(u >> 16);
}

__device__ __forceinline__ short8 pack8(float4 a, float4 b) {
    short8 o;
    o[0] = bf_rne(a.x); o[1] = bf_rne(a.y); o[2] = bf_rne(a.z); o[3] = bf_rne(a.w);
    o[4] = bf_rne(b.x); o[5] = bf_rne(b.y); o[6] = bf_rne(b.z); o[7] = bf_rne(b.w);
    return o;
}

__global__ __launch_bounds__(128) void gru_mfma4(
    const float* __restrict__ x,      // (S,B,1)
    const float* __restrict__ h_in,   // (2,B,H)
    const float* __restrict__ W_ih0,  // (96,1)
    const float* __restrict__ W_hh0,  // (96,32)
    const float* __restrict__ b_ih0,  // (96)
    const float* __restrict__ b_hh0,  // (96)
    const float* __restrict__ W_ih1,  // (96,32)
    const float* __restrict__ W_hh1,  // (96,32)
    const float* __restrict__ b_ih1,  // (96)
    const float* __restrict__ b_hh1,  // (96)
    const float* __restrict__ W_out,  // (1,32)
    const float* __restrict__ b_out,  // (1)
    float* __restrict__ out)          // y (S*B) then h_state (2,B,H)
{
    // Double-buffered transposed h tiles: [buf][batch-col n][hidden j].
    __shared__ __align__(16) float sh0[2][16 * PAD];
    __shared__ __align__(16) float sh1[2][16 * PAD];

    const int tid  = threadIdx.x;
    const int w    = tid >> 6;        // wave 0/1: gate rows [16w,16w+16)
    const int lane = tid & 63;
    const int n    = lane & 15;       // batch col (B/D) & A-row index
    const int q    = lane >> 4;       // quad
    const int bn   = blockIdx.x * 16 + n;

    const float SRZ = -1.4426950408889634f;  // -log2(e)   (sigmoid gates)
    const float SN  =  2.8853900817779268f;  //  2*log2(e) (tanh gate)

    // ---- persistent weight A-frags: A[m=n][k=q*8+e], pre-scaled bf16 ----
    short8 A0[3], Ai1[3], Ah1[3];            // t: 0=r, 1=z, 2=n
#pragma unroll
    for (int t = 0; t < 3; ++t) {
        const float sc = (t < 2) ? SRZ : SN;
        const int row = 32 * t + 16 * w + n;
        const float* p0 = W_hh0 + row * H_SZ + q * 8;
        const float* p1 = W_ih1 + row * H_SZ + q * 8;
        const float* p2 = W_hh1 + row * H_SZ + q * 8;
#pragma unroll
        for (int e = 0; e < 8; ++e) {
            A0[t][e]  = bf_rne(p0[e] * sc);
            Ai1[t][e] = bf_rne(p1[e] * sc);
            Ah1[t][e] = bf_rne(p2[e] * sc);
        }
    }

    // ---- bias C-inits (fp32, scaled). D row = 4q+r, col = n. ----
    f32x4 Cb0[3], C1rz[2], C1ni, C1nh;
#pragma unroll
    for (int t = 0; t < 3; ++t)
#pragma unroll
        for (int r = 0; r < 4; ++r) {
            const int g = 32 * t + 16 * w + 4 * q + r;
            if (t < 2) {
                Cb0[t][r]  = SRZ * (b_ih0[g] + b_hh0[g]);
                C1rz[t][r] = SRZ * (b_ih1[g] + b_hh1[g]);
            } else {
                Cb0[2][r] = SN * b_hh0[g];   // n-gate: b_hh stays on gh side
                C1ni[r]   = SN * b_ih1[g];
                C1nh[r]   = SN * b_hh1[g];
            }
        }
    const f32x4 Z4 = {0.f, 0.f, 0.f, 0.f};

    // ---- layer-0 input weights (per-lane j = 16w+4q+r) + head weights ----
    float wi0r[4], wi0z[4], wi0n[4], bi0n[4];
#pragma unroll
    for (int r = 0; r < 4; ++r) {
        const int j = 16 * w + 4 * q + r;
        wi0r[r] = SRZ * W_ih0[j];
        wi0z[r] = SRZ * W_ih0[32 + j];
        wi0n[r] = SN  * W_ih0[64 + j];
        bi0n[r] = SN  * b_ih0[64 + j];
    }
    // head weights for the B-read-side y computation: j = 8q+e
    float wo8[8];
#pragma unroll
    for (int e = 0; e < 8; ++e) wo8[e] = W_out[q * 8 + e];
    const float bout = b_out[0];

    // ---- h state init ----
    float h0d[4], h1d[4];
    {
        const float4 a = *(const float4*)&h_in[bn * H_SZ + 16 * w + 4 * q];
        const float4 b = *(const float4*)&h_in[B_SZ * H_SZ + bn * H_SZ + 16 * w + 4 * q];
        h0d[0] = a.x; h0d[1] = a.y; h0d[2] = a.z; h0d[3] = a.w;
        h1d[0] = b.x; h1d[1] = b.y; h1d[2] = b.z; h1d[3] = b.w;
    }
    short8 B0, B1;
    {
        const float4 a = *(const float4*)&h_in[bn * H_SZ + q * 8];
        const float4 b = *(const float4*)&h_in[bn * H_SZ + q * 8 + 4];
        B0 = pack8(a, b);
    }
    // preload sh1[0] with initial h1 (transposed) for step 0's post-barrier read
    *(float4*)&sh1[0][n * PAD + 16 * w + 4 * q] =
        make_float4(h1d[0], h1d[1], h1d[2], h1d[3]);

    float xcur = x[bn];

#pragma unroll 1
    for (int t = 0; t < S_LEN; ++t) {
        // ---- top: L0 MFMAs (independent, C = folded biases) ----
        f32x4 g0r = MFMA(A0[0], B0, Cb0[0]);
        f32x4 g0z = MFMA(A0[1], B0, Cb0[1]);
        f32x4 g0n = MFMA(A0[2], B0, Cb0[2]);
        const float xnext = (t + 1 < S_LEN) ? x[(t + 1) * B_SZ + bn] : 0.0f;

        // ---- L0 epilogue ----
        float hv4[4];
#pragma unroll
        for (int r = 0; r < 4; ++r) {
            const float rg = sigm_pre(fmaf(xcur, wi0r[r], g0r[r]));
            const float zg = sigm_pre(fmaf(xcur, wi0z[r], g0z[r]));
            const float ng = tanh_pre(fmaf(rg, g0n[r],
                                           fmaf(xcur, wi0n[r], bi0n[r])));
            const float hv = fmaf(zg, h0d[r] - ng, ng);
            h0d[r] = hv;
            hv4[r] = hv;
        }
        const int buf = t & 1;
        *(float4*)&sh0[buf][n * PAD + 16 * w + 4 * q] =
            make_float4(hv4[0], hv4[1], hv4[2], hv4[3]);

        __syncthreads();   // the ONE barrier per step

        // ---- mid: read fresh h0 (this step) and h1 (after step t-1) ----
        const float4 a0 = *(const float4*)&sh0[buf][n * PAD + q * 8];
        const float4 a1 = *(const float4*)&sh0[buf][n * PAD + q * 8 + 4];
        const float4 c0 = *(const float4*)&sh1[buf][n * PAD + q * 8];
        const float4 c1 = *(const float4*)&sh1[buf][n * PAD + q * 8 + 4];
        B0 = pack8(a0, a1);
        B1 = pack8(c0, c1);

        // y[t-1] from the fp32 h1(t-1) values just read (skip t==0: init h1)
        if (t > 0) {
            float ys = wo8[0] * c0.x;
            ys = fmaf(wo8[1], c0.y, ys);
            ys = fmaf(wo8[2], c0.z, ys);
            ys = fmaf(wo8[3], c0.w, ys);
            ys = fmaf(wo8[4], c1.x, ys);
            ys = fmaf(wo8[5], c1.y, ys);
            ys = fmaf(wo8[6], c1.z, ys);
            ys = fmaf(wo8[7], c1.w, ys);
            ys += __shfl_xor(ys, 16);
            ys += __shfl_xor(ys, 32);
            if (w == 0 && lane < 16) out[(t - 1) * B_SZ + bn] = ys + bout;
        }

        // ---- L1 MFMAs: hh-side and ih-side independent, sum in epilogue ----
        const f32x4 ur  = MFMA(Ah1[0], B1, C1rz[0]);
        const f32x4 uz  = MFMA(Ah1[1], B1, C1rz[1]);
        const f32x4 ghn = MFMA(Ah1[2], B1, C1nh);
        const f32x4 vr  = MFMA(Ai1[0], B0, Z4);
        const f32x4 vz  = MFMA(Ai1[1], B0, Z4);
        const f32x4 gin = MFMA(Ai1[2], B0, C1ni);

        // ---- L1 epilogue ----
#pragma unroll
        for (int r = 0; r < 4; ++r) {
            const float rg = sigm_pre(ur[r] + vr[r]);
            const float zg = sigm_pre(uz[r] + vz[r]);
            const float ng = tanh_pre(fmaf(rg, ghn[r], gin[r]));
            const float hv = fmaf(zg, h1d[r] - ng, ng);
            h1d[r] = hv;
            hv4[r] = hv;
        }
        // write h1 for step t+1's post-barrier read (other buffer)
        *(float4*)&sh1[buf ^ 1][n * PAD + 16 * w + 4 * q] =
            make_float4(hv4[0], hv4[1], hv4[2], hv4[3]);

        xcur = xnext;
    }

    // ---- y[S-1]: one more barrier + read of the last h1 write (buf 0) ----
    __syncthreads();
    {
        const float4 c0 = *(const float4*)&sh1[0][n * PAD + q * 8];
        const float4 c1 = *(const float4*)&sh1[0][n * PAD + q * 8 + 4];
        float ys = wo8[0] * c0.x;
        ys = fmaf(wo8[1], c0.y, ys);
        ys = fmaf(wo8[2], c0.z, ys);
        ys = fmaf(wo8[3], c0.w, ys);
        ys = fmaf(wo8[4], c1.x, ys);
        ys = fmaf(wo8[5], c1.y, ys);
        ys = fmaf(wo8[6], c1.z, ys);
        ys = fmaf(wo8[7], c1.w, ys);
        ys += __shfl_xor(ys, 16);
        ys += __shfl_xor(ys, 32);
        if (w == 0 && lane < 16) out[(S_LEN - 1) * B_SZ + bn] = ys + bout;
    }

    // ---- final h_state: out = y (S*B) ++ h0 (B*H) ++ h1 (B*H) ----
    const int jbase = 16 * w + 4 * q;
    *(float4*)&out[S_LEN * B_SZ + bn * H_SZ + jbase] =
        make_float4(h0d[0], h0d[1], h0d[2], h0d[3]);
    *(float4*)&out[S_LEN * B_SZ + B_SZ * H_SZ + bn * H_SZ + jbase] =
        make_float4(h1d[0], h1d[1], h1d[2], h1d[3]);
}

extern "C" void kernel_launch(void* const* d_in, const int* in_sizes, int n_in,
                              void* d_out, int out_size, void* d_ws, size_t ws_size,
                              hipStream_t stream) {
    (void)in_sizes; (void)n_in; (void)out_size; (void)d_ws; (void)ws_size;
    const float* x     = (const float*)d_in[0];
    const float* h_in  = (const float*)d_in[1];
    const float* W_ih0 = (const float*)d_in[2];
    const float* W_hh0 = (const float*)d_in[3];
    const float* b_ih0 = (const float*)d_in[4];
    const float* b_hh0 = (const float*)d_in[5];
    const float* W_ih1 = (const float*)d_in[6];
    const float* W_hh1 = (const float*)d_in[7];
    const float* b_ih1 = (const float*)d_in[8];
    const float* b_hh1 = (const float*)d_in[9];
    const float* W_out = (const float*)d_in[10];
    const float* b_out = (const float*)d_in[11];

    dim3 grid(B_SZ / 16);   // 512 blocks x 2 waves = 1024 waves (1/SIMD)
    dim3 block(128);
    gru_mfma4<<<grid, block, 0, stream>>>(x, h_in, W_ih0, W_hh0, b_ih0, b_hh0,
                                          W_ih1, W_hh1, b_ih1, b_hh1,
                                          W_out, b_out, (float*)d_out);
}

// Round 5
// 299.960 us; speedup vs baseline: 1.2908x; 1.2034x over previous
//
#include <hip/hip_runtime.h>

// Fused 2-layer GRU, round 5: layer-pipelined waves + no global ops in loop.
// S=256, B=8192, IN=1, H=32, L=2.
//
// 512 blocks x 256 thr (4 waves); each block owns 16 batch elements.
// Waves 0,1: layer 0 (gate-row halves 16*w .. 16*w+16 of r,z,n).
// Waves 2,3: layer 1, lagged ONE step (L1 step t needs h0(t)).
// Per iteration i (0..S inclusive):
//   pre-barrier : w01 compute h0(i) from B0=h0(i-1); write sh0[buf].
//                 w23 compute h1(i-1) from B0=h0(i-1) (ih) + B1=h1(i-2) (hh);
//                 write sh1[buf].
//   barrier (waits lgkmcnt only -- NO global ops in the loop: x is staged
//            in LDS up front, y buffered in LDS and flushed at the end).
//   post-barrier: all waves read sh0[buf] -> B0 = h0(i) (bf16 pack);
//                 w23 read sh1[buf] -> B1 = h1(i-1); wave 2 computes
//                 y(i-1) from those fp32 values -> sy.
// sh0/sh1 triple-buffered => no cross-barrier write/read timing assumptions.
// h carried as single RNE bf16 through MFMA (absmax 0.0078 in R4).

#define S_LEN 256
#define B_SZ  8192
#define H_SZ  32
#define PAD   36     // LDS row stride (floats)

typedef __attribute__((ext_vector_type(8))) short short8;  // 8 bf16
typedef __attribute__((ext_vector_type(4))) float f32x4;   // MFMA C/D

#define MFMA(a, b, c) __builtin_amdgcn_mfma_f32_16x16x32_bf16(a, b, c, 0, 0, 0)

#if __has_builtin(__builtin_amdgcn_exp2f)
#define EXP2F(x) __builtin_amdgcn_exp2f(x)
#else
#define EXP2F(x) exp2f(x)
#endif
#if __has_builtin(__builtin_amdgcn_rcpf)
#define RCPF(x) __builtin_amdgcn_rcpf(x)
#else
#define RCPF(x) (1.0f / (x))
#endif

__device__ __forceinline__ float sigm_pre(float p) {   // p = -log2e * v
    return RCPF(1.0f + EXP2F(p));
}
__device__ __forceinline__ float tanh_pre(float p) {   // p = 2*log2e * v
    return 1.0f - 2.0f * RCPF(1.0f + EXP2F(p));
}

__device__ __forceinline__ short bf_rne(float f) {
    union { float f; unsigned u; } x; x.f = f;
    unsigned u = x.u + 0x7fffu + ((x.u >> 16) & 1u);
    return (short)(u >> 16);
}

__device__ __forceinline__ short8 pack8(float4 a, float4 b) {
    short8 o;
    o[0] = bf_rne(a.x); o[1] = bf_rne(a.y); o[2] = bf_rne(a.z); o[3] = bf_rne(a.w);
    o[4] = bf_rne(b.x); o[5] = bf_rne(b.y); o[6] = bf_rne(b.z); o[7] = bf_rne(b.w);
    return o;
}

__global__ __launch_bounds__(256) void gru_pipe(
    const float* __restrict__ x,      // (S,B,1)
    const float* __restrict__ h_in,   // (2,B,H)
    const float* __restrict__ W_ih0,  // (96,1)
    const float* __restrict__ W_hh0,  // (96,32)
    const float* __restrict__ b_ih0,  // (96)
    const float* __restrict__ b_hh0,  // (96)
    const float* __restrict__ W_ih1,  // (96,32)
    const float* __restrict__ W_hh1,  // (96,32)
    const float* __restrict__ b_ih1,  // (96)
    const float* __restrict__ b_hh1,  // (96)
    const float* __restrict__ W_out,  // (1,32)
    const float* __restrict__ b_out,  // (1)
    float* __restrict__ out)          // y (S*B) then h_state (2,B,H)
{
    __shared__ __align__(16) float sx[S_LEN * 16];        // staged x
    __shared__ __align__(16) float sy[S_LEN * 16];        // buffered y
    __shared__ __align__(16) float sh0[3][16 * PAD];      // h0 exchange
    __shared__ __align__(16) float sh1[3][16 * PAD];      // h1 exchange

    const int tid  = threadIdx.x;
    const int w    = tid >> 6;        // 0,1 -> layer 0; 2,3 -> layer 1
    const int lane = tid & 63;
    const int n    = lane & 15;       // batch col / A-row index
    const int q    = lane >> 4;       // quad
    const int base = blockIdx.x * 16;
    const int bn   = base + n;
    const int wl   = w & 1;           // gate-row half within the layer

    // ---- stage x into LDS (one-time, coalesced float4) ----
    for (int s = tid; s < S_LEN * 4; s += 256) {
        const int t = s >> 2, c = s & 3;
        *(float4*)&sx[t * 16 + c * 4] = *(const float4*)&x[t * B_SZ + base + c * 4];
    }

    const float SRZ = -1.4426950408889634f;  // -log2(e)   (sigmoid gates)
    const float SN  =  2.8853900817779268f;  //  2*log2(e) (tanh gate)

    // ---- per-role persistent weights ----
    short8 A_h[3], A_i[3];       // hh-side (or L0) / L1 ih-side A-frags
    f32x4  C_h[3], C_i3;         // folded-bias C operands
    float  wi0r[4], wi0z[4], wi0n[4], bi0n[4];   // L0 input weights
    float  wo8[8], bout = 0.f;                   // head (waves 2,3)
    float  hd[4];                                // own h half, D-layout fp32

    if (w < 2) {
#pragma unroll
        for (int t = 0; t < 3; ++t) {
            const float sc = (t < 2) ? SRZ : SN;
            const int row = 32 * t + 16 * wl + n;
#pragma unroll
            for (int e = 0; e < 8; ++e)
                A_h[t][e] = bf_rne(W_hh0[row * H_SZ + q * 8 + e] * sc);
#pragma unroll
            for (int r = 0; r < 4; ++r) {
                const int g = 32 * t + 16 * wl + 4 * q + r;
                C_h[t][r] = (t < 2) ? SRZ * (b_ih0[g] + b_hh0[g])
                                    : SN * b_hh0[g];
            }
        }
#pragma unroll
        for (int r = 0; r < 4; ++r) {
            const int j = 16 * wl + 4 * q + r;
            wi0r[r] = SRZ * W_ih0[j];
            wi0z[r] = SRZ * W_ih0[32 + j];
            wi0n[r] = SN  * W_ih0[64 + j];
            bi0n[r] = SN  * b_ih0[64 + j];
            hd[r]   = h_in[bn * H_SZ + j];
        }
    } else {
#pragma unroll
        for (int t = 0; t < 3; ++t) {
            const float sc = (t < 2) ? SRZ : SN;
            const int row = 32 * t + 16 * wl + n;
#pragma unroll
            for (int e = 0; e < 8; ++e) {
                A_h[t][e] = bf_rne(W_hh1[row * H_SZ + q * 8 + e] * sc);
                A_i[t][e] = bf_rne(W_ih1[row * H_SZ + q * 8 + e] * sc);
            }
#pragma unroll
            for (int r = 0; r < 4; ++r) {
                const int g = 32 * t + 16 * wl + 4 * q + r;
                C_h[t][r] = (t < 2) ? SRZ * (b_ih1[g] + b_hh1[g])
                                    : SN * b_hh1[g];
                if (t == 2) C_i3[r] = SN * b_ih1[g];
            }
        }
#pragma unroll
        for (int r = 0; r < 4; ++r)
            hd[r] = h_in[B_SZ * H_SZ + bn * H_SZ + 16 * wl + 4 * q + r];
#pragma unroll
        for (int e = 0; e < 8; ++e) wo8[e] = W_out[q * 8 + e];
        bout = b_out[0];
    }
    const f32x4 Z4 = {0.f, 0.f, 0.f, 0.f};

    // ---- initial B fragments from h_in ----
    short8 B0, B1;
    {
        const float4 a = *(const float4*)&h_in[bn * H_SZ + q * 8];
        const float4 b = *(const float4*)&h_in[bn * H_SZ + q * 8 + 4];
        B0 = pack8(a, b);
        const float4 c = *(const float4*)&h_in[B_SZ * H_SZ + bn * H_SZ + q * 8];
        const float4 d = *(const float4*)&h_in[B_SZ * H_SZ + bn * H_SZ + q * 8 + 4];
        B1 = pack8(c, d);
    }

    __syncthreads();   // x staged

    int buf = 0;
#pragma unroll 1
    for (int i = 0; i <= S_LEN; ++i) {
        // ---------------- pre-barrier compute ----------------
        if (w < 2) {
            if (i < S_LEN) {
                const f32x4 g0r = MFMA(A_h[0], B0, C_h[0]);
                const f32x4 g0z = MFMA(A_h[1], B0, C_h[1]);
                const f32x4 g0n = MFMA(A_h[2], B0, C_h[2]);
                const float xc = sx[i * 16 + n];
                float hv4[4];
#pragma unroll
                for (int r = 0; r < 4; ++r) {
                    const float rg = sigm_pre(fmaf(xc, wi0r[r], g0r[r]));
                    const float zg = sigm_pre(fmaf(xc, wi0z[r], g0z[r]));
                    const float ng = tanh_pre(fmaf(rg, g0n[r],
                                                   fmaf(xc, wi0n[r], bi0n[r])));
                    const float hv = fmaf(zg, hd[r] - ng, ng);
                    hd[r] = hv;
                    hv4[r] = hv;
                }
                *(float4*)&sh0[buf][n * PAD + 16 * wl + 4 * q] =
                    make_float4(hv4[0], hv4[1], hv4[2], hv4[3]);
            }
        } else {
            if (i > 0) {
                // h1(i-1) = f(h0(i-1)=B0, h1(i-2)=B1, hd)
                const f32x4 ur = MFMA(A_h[0], B1, C_h[0]);
                const f32x4 uz = MFMA(A_h[1], B1, C_h[1]);
                const f32x4 un = MFMA(A_h[2], B1, C_h[2]);
                const f32x4 vr = MFMA(A_i[0], B0, Z4);
                const f32x4 vz = MFMA(A_i[1], B0, Z4);
                const f32x4 vn = MFMA(A_i[2], B0, C_i3);
                float hv4[4];
#pragma unroll
                for (int r = 0; r < 4; ++r) {
                    const float rg = sigm_pre(ur[r] + vr[r]);
                    const float zg = sigm_pre(uz[r] + vz[r]);
                    const float ng = tanh_pre(fmaf(rg, un[r], vn[r]));
                    const float hv = fmaf(zg, hd[r] - ng, ng);
                    hd[r] = hv;
                    hv4[r] = hv;
                }
                *(float4*)&sh1[buf][n * PAD + 16 * wl + 4 * q] =
                    make_float4(hv4[0], hv4[1], hv4[2], hv4[3]);
            }
        }

        __syncthreads();   // lgkm-only drain: no global ops in this loop

        // ---------------- post-barrier reads/packs ----------------
        if (i < S_LEN) {
            const float4 a0 = *(const float4*)&sh0[buf][n * PAD + q * 8];
            const float4 a1 = *(const float4*)&sh0[buf][n * PAD + q * 8 + 4];
            B0 = pack8(a0, a1);   // h0(i): w01 next L0, w23 next L1 ih-side
        }
        if (w >= 2 && i > 0) {
            const float4 c0 = *(const float4*)&sh1[buf][n * PAD + q * 8];
            const float4 c1 = *(const float4*)&sh1[buf][n * PAD + q * 8 + 4];
            B1 = pack8(c0, c1);   // h1(i-1)
            if (w == 2) {
                float ys = wo8[0] * c0.x;
                ys = fmaf(wo8[1], c0.y, ys);
                ys = fmaf(wo8[2], c0.z, ys);
                ys = fmaf(wo8[3], c0.w, ys);
                ys = fmaf(wo8[4], c1.x, ys);
                ys = fmaf(wo8[5], c1.y, ys);
                ys = fmaf(wo8[6], c1.z, ys);
                ys = fmaf(wo8[7], c1.w, ys);
                ys += __shfl_xor(ys, 16);
                ys += __shfl_xor(ys, 32);
                if (lane < 16) sy[(i - 1) * 16 + n] = ys + bout;
            }
        }
        buf = (buf == 2) ? 0 : buf + 1;
    }

    __syncthreads();   // sy complete

    // ---- flush y (coalesced float4) ----
    for (int s = tid; s < S_LEN * 4; s += 256) {
        const int t = s >> 2, c = s & 3;
        *(float4*)&out[t * B_SZ + base + c * 4] = *(const float4*)&sy[t * 16 + c * 4];
    }

    // ---- final h_state: out = y (S*B) ++ h0 (B*H) ++ h1 (B*H) ----
    const int j = 16 * wl + 4 * q;
    if (w < 2)
        *(float4*)&out[S_LEN * B_SZ + bn * H_SZ + j] =
            make_float4(hd[0], hd[1], hd[2], hd[3]);
    else
        *(float4*)&out[S_LEN * B_SZ + B_SZ * H_SZ + bn * H_SZ + j] =
            make_float4(hd[0], hd[1], hd[2], hd[3]);
}

extern "C" void kernel_launch(void* const* d_in, const int* in_sizes, int n_in,
                              void* d_out, int out_size, void* d_ws, size_t ws_size,
                              hipStream_t stream) {
    (void)in_sizes; (void)n_in; (void)out_size; (void)d_ws; (void)ws_size;
    const float* x     = (const float*)d_in[0];
    const float* h_in  = (const float*)d_in[1];
    const float* W_ih0 = (const float*)d_in[2];
    const float* W_hh0 = (const float*)d_in[3];
    const float* b_ih0 = (const float*)d_in[4];
    const float* b_hh0 = (const float*)d_in[5];
    const float* W_ih1 = (const float*)d_in[6];
    const float* W_hh1 = (const float*)d_in[7];
    const float* b_ih1 = (const float*)d_in[8];
    const float* b_hh1 = (const float*)d_in[9];
    const float* W_out = (const float*)d_in[10];
    const float* b_out = (const float*)d_in[11];

    dim3 grid(B_SZ / 16);   // 512 blocks x 4 waves = 2048 waves (2/SIMD)
    dim3 block(256);
    gru_pipe<<<grid, block, 0, stream>>>(x, h_in, W_ih0, W_hh0, b_ih0, b_hh0,
                                         W_ih1, W_hh1, b_ih1, b_hh1,
                                         W_out, b_out, (float*)d_out);
}

// Round 6
// 268.976 us; speedup vs baseline: 1.4394x; 1.1152x over previous
//
#include <hip/hip_runtime.h>

// Fused 2-layer GRU, round 6: bf16 h-exchange (zero repack), layer-pipelined.
// S=256, B=8192, IN=1, H=32, L=2.
//
// 512 blocks x 256 thr (4 waves); block owns 16 batch elements.
// Waves 0,1: layer 0 (gate-row half 16*wl); waves 2,3: layer 1, lagged 1 step.
// h is exchanged through LDS in bf16: producers convert fp32->bf16 with
// v_cvt_pk_bf16_f32 (2 instr) and ds_write_b64; consumers ds_read_b128 the
// transposed row == the MFMA B-fragment directly (no per-consumer repack).
// Row stride 40 shorts (80 B): b128 reads 16B-aligned, 2-way banks (free).
// y partials computed from producer-local fp32 h1 (no readback); two
// per-half slabs summed at the final flush. No global ops inside the loop
// (x staged to LDS, y buffered in LDS). Triple-buffered h exchange.

#define S_LEN 256
#define B_SZ  8192
#define H_SZ  32
#define RS    40     // LDS row stride in shorts (80 B)

typedef __attribute__((ext_vector_type(8))) short short8;  // 8 bf16
typedef __attribute__((ext_vector_type(4))) float f32x4;   // MFMA C/D

#define MFMA(a, b, c) __builtin_amdgcn_mfma_f32_16x16x32_bf16(a, b, c, 0, 0, 0)

#if __has_builtin(__builtin_amdgcn_exp2f)
#define EXP2F(x) __builtin_amdgcn_exp2f(x)
#else
#define EXP2F(x) exp2f(x)
#endif
#if __has_builtin(__builtin_amdgcn_rcpf)
#define RCPF(x) __builtin_amdgcn_rcpf(x)
#else
#define RCPF(x) (1.0f / (x))
#endif

__device__ __forceinline__ float sigm_pre(float p) {   // p = -log2e * v
    return RCPF(1.0f + EXP2F(p));
}
__device__ __forceinline__ float tanh_pre(float p) {   // p = 2*log2e * v
    return 1.0f - 2.0f * RCPF(1.0f + EXP2F(p));
}

__device__ __forceinline__ unsigned short bf_rne1(float f) {
    union { float f; unsigned u; } x; x.f = f;
    unsigned u = x.u + 0x7fffu + ((x.u >> 16) & 1u);
    return (unsigned short)(u >> 16);
}

#if __has_builtin(__builtin_amdgcn_cvt_pk_bf16_f32)
typedef __bf16 bf16x2 __attribute__((ext_vector_type(2)));
__device__ __forceinline__ unsigned pk2(float a, float b) {
    union { bf16x2 v; unsigned u; } c;
    c.v = __builtin_amdgcn_cvt_pk_bf16_f32(a, b);
    return c.u;
}
#else
__device__ __forceinline__ unsigned pk2(float a, float b) {
    return (unsigned)bf_rne1(a) | ((unsigned)bf_rne1(b) << 16);
}
#endif

union Frag { short8 s8; unsigned u[4]; };

__global__ __launch_bounds__(256) void gru_bf(
    const float* __restrict__ x,      // (S,B,1)
    const float* __restrict__ h_in,   // (2,B,H)
    const float* __restrict__ W_ih0,  // (96,1)
    const float* __restrict__ W_hh0,  // (96,32)
    const float* __restrict__ b_ih0,  // (96)
    const float* __restrict__ b_hh0,  // (96)
    const float* __restrict__ W_ih1,  // (96,32)
    const float* __restrict__ W_hh1,  // (96,32)
    const float* __restrict__ b_ih1,  // (96)
    const float* __restrict__ b_hh1,  // (96)
    const float* __restrict__ W_out,  // (1,32)
    const float* __restrict__ b_out,  // (1)
    float* __restrict__ out)          // y (S*B) then h_state (2,B,H)
{
    __shared__ __align__(16) float sx[S_LEN * 16];            // staged x
    __shared__ __align__(16) float sy[2][S_LEN * 16];         // y partials
    __shared__ __align__(16) unsigned short sh0s[3][16 * RS]; // h0, bf16
    __shared__ __align__(16) unsigned short sh1s[3][16 * RS]; // h1, bf16

    const int tid  = threadIdx.x;
    const int w    = tid >> 6;        // 0,1 -> layer 0; 2,3 -> layer 1
    const int lane = tid & 63;
    const int n    = lane & 15;       // batch col / A-row index
    const int q    = lane >> 4;       // quad
    const int base = blockIdx.x * 16;
    const int bn   = base + n;
    const int wl   = w & 1;           // gate-row half within the layer

    // ---- stage x into LDS (one-time, coalesced float4) ----
    for (int s = tid; s < S_LEN * 4; s += 256) {
        const int t = s >> 2, c = s & 3;
        *(float4*)&sx[t * 16 + c * 4] = *(const float4*)&x[t * B_SZ + base + c * 4];
    }

    const float SRZ = -1.4426950408889634f;  // -log2(e)   (sigmoid gates)
    const float SN  =  2.8853900817779268f;  //  2*log2(e) (tanh gate)

    // ---- per-role persistent weights ----
    short8 A_h[3], A_i[3];
    f32x4  C_h[3], C_i3;
    float  wi0r[4], wi0z[4], wi0n[4], bi0n[4];   // L0 input weights
    float  wo[4];                                 // head (waves 2,3)
    float  hd[4];                                 // own h half, fp32

    if (w < 2) {
#pragma unroll
        for (int t = 0; t < 3; ++t) {
            const float sc = (t < 2) ? SRZ : SN;
            const int row = 32 * t + 16 * wl + n;
#pragma unroll
            for (int e = 0; e < 8; ++e)
                A_h[t][e] = (short)bf_rne1(W_hh0[row * H_SZ + q * 8 + e] * sc);
#pragma unroll
            for (int r = 0; r < 4; ++r) {
                const int g = 32 * t + 16 * wl + 4 * q + r;
                C_h[t][r] = (t < 2) ? SRZ * (b_ih0[g] + b_hh0[g])
                                    : SN * b_hh0[g];
            }
        }
#pragma unroll
        for (int r = 0; r < 4; ++r) {
            const int j = 16 * wl + 4 * q + r;
            wi0r[r] = SRZ * W_ih0[j];
            wi0z[r] = SRZ * W_ih0[32 + j];
            wi0n[r] = SN  * W_ih0[64 + j];
            bi0n[r] = SN  * b_ih0[64 + j];
            hd[r]   = h_in[bn * H_SZ + j];
            wo[r]   = 0.f;
        }
    } else {
#pragma unroll
        for (int t = 0; t < 3; ++t) {
            const float sc = (t < 2) ? SRZ : SN;
            const int row = 32 * t + 16 * wl + n;
#pragma unroll
            for (int e = 0; e < 8; ++e) {
                A_h[t][e] = (short)bf_rne1(W_hh1[row * H_SZ + q * 8 + e] * sc);
                A_i[t][e] = (short)bf_rne1(W_ih1[row * H_SZ + q * 8 + e] * sc);
            }
#pragma unroll
            for (int r = 0; r < 4; ++r) {
                const int g = 32 * t + 16 * wl + 4 * q + r;
                C_h[t][r] = (t < 2) ? SRZ * (b_ih1[g] + b_hh1[g])
                                    : SN * b_hh1[g];
                if (t == 2) C_i3[r] = SN * b_ih1[g];
            }
        }
#pragma unroll
        for (int r = 0; r < 4; ++r) {
            const int j = 16 * wl + 4 * q + r;
            hd[r] = h_in[B_SZ * H_SZ + bn * H_SZ + j];
            wo[r] = W_out[j];
        }
    }
    const f32x4 Z4 = {0.f, 0.f, 0.f, 0.f};
    const float bout = b_out[0];

    // ---- initial B fragments: pack h_in fp32 -> bf16 ----
    short8 B0, B1;
    {
        Frag f;
        const float4 a = *(const float4*)&h_in[bn * H_SZ + q * 8];
        const float4 b = *(const float4*)&h_in[bn * H_SZ + q * 8 + 4];
        f.u[0] = pk2(a.x, a.y); f.u[1] = pk2(a.z, a.w);
        f.u[2] = pk2(b.x, b.y); f.u[3] = pk2(b.z, b.w);
        B0 = f.s8;
        const float4 c = *(const float4*)&h_in[B_SZ * H_SZ + bn * H_SZ + q * 8];
        const float4 d = *(const float4*)&h_in[B_SZ * H_SZ + bn * H_SZ + q * 8 + 4];
        f.u[0] = pk2(c.x, c.y); f.u[1] = pk2(c.z, c.w);
        f.u[2] = pk2(d.x, d.y); f.u[3] = pk2(d.z, d.w);
        B1 = f.s8;
    }

    __syncthreads();   // x staged

    int buf = 0;
#pragma unroll 1
    for (int i = 0; i <= S_LEN; ++i) {
        // ---------------- pre-barrier compute ----------------
        if (w < 2) {
            if (i < S_LEN) {
                const float xc = sx[i * 16 + n];
                const f32x4 g0r = MFMA(A_h[0], B0, C_h[0]);
                const f32x4 g0z = MFMA(A_h[1], B0, C_h[1]);
                const f32x4 g0n = MFMA(A_h[2], B0, C_h[2]);
                float hv4[4];
#pragma unroll
                for (int r = 0; r < 4; ++r) {
                    const float rg = sigm_pre(fmaf(xc, wi0r[r], g0r[r]));
                    const float zg = sigm_pre(fmaf(xc, wi0z[r], g0z[r]));
                    const float ng = tanh_pre(fmaf(rg, g0n[r],
                                                   fmaf(xc, wi0n[r], bi0n[r])));
                    const float hv = fmaf(zg, hd[r] - ng, ng);
                    hd[r] = hv;
                    hv4[r] = hv;
                }
                // bf16 write: 8 B at row n, hidden offset 16*wl+4*q
                *(uint2*)&sh0s[buf][n * RS + 16 * wl + 4 * q] =
                    make_uint2(pk2(hv4[0], hv4[1]), pk2(hv4[2], hv4[3]));
            }
        } else {
            if (i > 0) {
                // h1(i-1) = f(h0(i-1)=B0, h1(i-2)=B1, hd)
                const f32x4 ur = MFMA(A_h[0], B1, C_h[0]);
                const f32x4 uz = MFMA(A_h[1], B1, C_h[1]);
                const f32x4 un = MFMA(A_h[2], B1, C_h[2]);
                const f32x4 vr = MFMA(A_i[0], B0, Z4);
                const f32x4 vz = MFMA(A_i[1], B0, Z4);
                const f32x4 vn = MFMA(A_i[2], B0, C_i3);
                float hv4[4];
                float ys = 0.f;
#pragma unroll
                for (int r = 0; r < 4; ++r) {
                    const float rg = sigm_pre(ur[r] + vr[r]);
                    const float zg = sigm_pre(uz[r] + vz[r]);
                    const float ng = tanh_pre(fmaf(rg, un[r], vn[r]));
                    const float hv = fmaf(zg, hd[r] - ng, ng);
                    hd[r] = hv;
                    hv4[r] = hv;
                    ys = fmaf(hv, wo[r], ys);
                }
                *(uint2*)&sh1s[buf][n * RS + 16 * wl + 4 * q] =
                    make_uint2(pk2(hv4[0], hv4[1]), pk2(hv4[2], hv4[3]));
                // y partial for this half: reduce over q, store per (t, n)
                ys += __shfl_xor(ys, 16);
                ys += __shfl_xor(ys, 32);
                if (lane < 16) sy[wl][(i - 1) * 16 + n] = ys;
            }
        }

        __syncthreads();   // lgkm-only drain (no global ops in loop)

        // ---------------- post-barrier reads: B-frags direct from LDS ----
        if (i < S_LEN)
            B0 = *(const short8*)&sh0s[buf][n * RS + q * 8];
        if (w >= 2 && i > 0)
            B1 = *(const short8*)&sh1s[buf][n * RS + q * 8];

        buf = (buf == 2) ? 0 : buf + 1;
    }

    __syncthreads();   // sy complete

    // ---- flush y: sum the two half-partials, coalesced float4 stores ----
    for (int s = tid; s < S_LEN * 4; s += 256) {
        const int t = s >> 2, c = s & 3;
        const float4 a = *(const float4*)&sy[0][t * 16 + c * 4];
        const float4 b = *(const float4*)&sy[1][t * 16 + c * 4];
        *(float4*)&out[t * B_SZ + base + c * 4] =
            make_float4(a.x + b.x + bout, a.y + b.y + bout,
                        a.z + b.z + bout, a.w + b.w + bout);
    }

    // ---- final h_state: out = y (S*B) ++ h0 (B*H) ++ h1 (B*H) ----
    const int j = 16 * wl + 4 * q;
    if (w < 2)
        *(float4*)&out[S_LEN * B_SZ + bn * H_SZ + j] =
            make_float4(hd[0], hd[1], hd[2], hd[3]);
    else
        *(float4*)&out[S_LEN * B_SZ + B_SZ * H_SZ + bn * H_SZ + j] =
            make_float4(hd[0], hd[1], hd[2], hd[3]);
}

extern "C" void kernel_launch(void* const* d_in, const int* in_sizes, int n_in,
                              void* d_out, int out_size, void* d_ws, size_t ws_size,
                              hipStream_t stream) {
    (void)in_sizes; (void)n_in; (void)out_size; (void)d_ws; (void)ws_size;
    const float* x     = (const float*)d_in[0];
    const float* h_in  = (const float*)d_in[1];
    const float* W_ih0 = (const float*)d_in[2];
    const float* W_hh0 = (const float*)d_in[3];
    const float* b_ih0 = (const float*)d_in[4];
    const float* b_hh0 = (const float*)d_in[5];
    const float* W_ih1 = (const float*)d_in[6];
    const float* W_hh1 = (const float*)d_in[7];
    const float* b_ih1 = (const float*)d_in[8];
    const float* b_hh1 = (const float*)d_in[9];
    const float* W_out = (const float*)d_in[10];
    const float* b_out = (const float*)d_in[11];

    dim3 grid(B_SZ / 16);   // 512 blocks x 4 waves = 2048 waves (2/SIMD)
    dim3 block(256);
    gru_bf<<<grid, block, 0, stream>>>(x, h_in, W_ih0, W_hh0, b_ih0, b_hh0,
                                       W_ih1, W_hh1, b_ih1, b_hh1,
                                       W_out, b_out, (float*)d_out);
}